// Round 15
// baseline (263.152 us; speedup 1.0000x reference)
//
#include <hip/hip_runtime.h>
#include <hip/hip_bf16.h>

typedef __attribute__((ext_vector_type(4))) int i32x4;

#define GLOBAL_CAST(p) (const __attribute__((address_space(1))) void*)(p)
#define LDS_CAST(p)    (__attribute__((address_space(3))) void*)(p)

// ---------------------------------------------------------------------------
// Kernel 1: per-row scale = max(mean(|w|), eps); q = ternary(w) as i8
// (row-major; feeds the B LDS-staging path).
// ---------------------------------------------------------------------------
__global__ __launch_bounds__(256) void scale_quant_kernel(
    const float* __restrict__ w, float* __restrict__ scale,
    signed char* __restrict__ q, int K)
{
    const int row = blockIdx.x;
    const int tid = threadIdx.x;
    const float* wrow = w + (size_t)row * K;

    float s = 0.f;
    const int nvec = K >> 2;
    const float4* wv = (const float4*)wrow;
    for (int i = tid; i < nvec; i += blockDim.x) {
        float4 v = wv[i];
        s += fabsf(v.x) + fabsf(v.y) + fabsf(v.z) + fabsf(v.w);
    }
    #pragma unroll
    for (int off = 32; off > 0; off >>= 1) s += __shfl_down(s, off);

    __shared__ float red[4];
    const int lane = tid & 63, wid = tid >> 6;
    if (lane == 0) red[wid] = s;
    __syncthreads();
    const float total = red[0] + red[1] + red[2] + red[3];
    const float sc = fmaxf(total / (float)K, 1e-6f);
    const float thr = sc * 0.75f;
    if (tid == 0) scale[row] = sc;

    if (q != nullptr) {
        char4* qv = (char4*)(q + (size_t)row * K);
        for (int i = tid; i < nvec; i += blockDim.x) {
            float4 v = wv[i];
            char4 o;
            o.x = (v.x >= thr) ? 1 : ((v.x <= -thr) ? -1 : 0);
            o.y = (v.y >= thr) ? 1 : ((v.y <= -thr) ? -1 : 0);
            o.z = (v.z >= thr) ? 1 : ((v.z <= -thr) ? -1 : 0);
            o.w = (v.w >= thr) ? 1 : ((v.w <= -thr) ? -1 : 0);
            qv[i] = o;
        }
    }
}

// ---------------------------------------------------------------------------
// Kernel 2: per-row symmetric i8 quantization of x -> FRAGMENT-TILED layout.
//   tiled addr of 16B chunk (row R, chunk C=k/16):
//     g = R>>4 :  xqt + g*(16*K) + C*256 + (R&15)*16
//   so a wave reading rows R0..R0+15 x chunks C0..C0+3 is 1KB contiguous.
// One block per 16-row group; pass1 amax, pass2 quantize (coalesced writes).
// ---------------------------------------------------------------------------
__global__ __launch_bounds__(256) void x_quant_tiled_kernel(
    const float* __restrict__ x, float* __restrict__ sx,
    signed char* __restrict__ xqt, int K)
{
    const int g   = blockIdx.x;
    const int tid = threadIdx.x;
    const int R0  = g * 16;
    const int rowf4 = K >> 2;

    // ---- pass 1: per-row absmax over the 16-row slab ----
    const float4* xv = (const float4*)(x + (size_t)R0 * K);
    float amx[16];
    #pragma unroll
    for (int r = 0; r < 16; ++r) amx[r] = 0.f;
    #pragma unroll
    for (int r = 0; r < 16; ++r) {
        for (int i = tid; i < rowf4; i += 256) {
            float4 v = xv[(size_t)r * rowf4 + i];
            amx[r] = fmaxf(amx[r], fmaxf(fmaxf(fabsf(v.x), fabsf(v.y)),
                                         fmaxf(fabsf(v.z), fabsf(v.w))));
        }
    }
    __shared__ float redl[16][4];
    __shared__ float sinv[16];
    const int lane = tid & 63, wv = tid >> 6;
    #pragma unroll
    for (int r = 0; r < 16; ++r) {
        float a = amx[r];
        #pragma unroll
        for (int off = 32; off > 0; off >>= 1) a = fmaxf(a, __shfl_down(a, off));
        if (lane == 0) redl[r][wv] = a;
    }
    __syncthreads();
    if (tid < 16) {
        const float a = fmaxf(fmaxf(redl[tid][0], redl[tid][1]),
                              fmaxf(redl[tid][2], redl[tid][3]));
        sx[R0 + tid] = a * (1.f / 127.f);
        sinv[tid] = (a > 0.f) ? (127.f / a) : 0.f;
    }
    __syncthreads();

    // ---- pass 2: quantize into tiled layout (fully coalesced 16B writes) ----
    const int r  = tid & 15;
    const int cb = tid >> 4;
    const float inv = sinv[r];
    const float* xrow = x + (size_t)(R0 + r) * K;
    signed char* outg = xqt + (size_t)g * (16 * (size_t)K);
    const int nj = K >> 8;   // chunks per row = K/16; cb covers 16 -> j loop K/256
    for (int j = 0; j < nj; ++j) {
        const int C = cb + 16 * j;
        const float* xp = xrow + C * 16;
        int w[4];
        #pragma unroll
        for (int p = 0; p < 4; ++p) {
            float4 v = *(const float4*)(xp + p * 4);
            const int b0 = __float2int_rn(v.x * inv) & 255;
            const int b1 = __float2int_rn(v.y * inv) & 255;
            const int b2 = __float2int_rn(v.z * inv) & 255;
            const int b3 = __float2int_rn(v.w * inv) & 255;
            w[p] = b0 | (b1 << 8) | (b2 << 16) | (b3 << 24);
        }
        i32x4 pk = { w[0], w[1], w[2], w[3] };
        *(i32x4*)(outg + (size_t)C * 256 + r * 16) = pk;
    }
}

// ---------------------------------------------------------------------------
// Kernel 3: 256x256 i8 GEMM, A DIRECT FROM GLOBAL (tiled, coalesced reg
// loads), B via r12's proven LDS path. mfma_i32_16x16x64_i8.
//   out[m][n] = sx[m]*scale[n] * (sum_k xq[m][k]*q[n][k]) + bias[n]
// 512 thr = 8 waves (2M x 4N); per-wave 128x64 out = acc[8][4] i32x4 (AGPR).
// A: per-wave fragment = 1KB contiguous global_load_dwordx4 (lane l =
//   chunk kh=l>>4, row lr=l&15 of a 16-row group); 16 loads/wave/K-tile,
//   counted-async, consumed from registers -> no LDS, no barrier coupling.
// B: LDS 64 KiB = 2 dbuf x 32KB, r12 chunk swizzle (slot s of row r holds
//   global chunk s^(r&7); dest linear, source pre-swizzled; 0 conflicts).
// RACE FIX vs r14: prologue uses vmcnt(0) -- vmcnt(8) assumed the 4 B-stage
// DMAs were oldest in the VMEM queue, but the compiler may reorder the 8 A
// register loads ahead of them, making the count guarantee nothing (tripwire
// divergence). vmcnt(0) is issue-order-independent. Tile-end wait was
// already vmcnt(0).
// i32 accumulation exact; error = X-quant only.
// ---------------------------------------------------------------------------
#define BM 256
#define BN 256
#define BK 128

__global__ __launch_bounds__(512, 2) void gemm256_i8_kernel(
    const signed char* __restrict__ Xqt,  // fragment-tiled [M/16][K/16][16][16]
    const signed char* __restrict__ Qq,   // [N][K] row-major i8
    const float* __restrict__ sx,         // [M]
    const float* __restrict__ scale,      // [N]
    const float* __restrict__ bias,       // [N]
    float* __restrict__ out, int M, int N, int K)
{
    __shared__ __align__(16) char lds[65536];

    const int tid  = threadIdx.x;
    const int lane = tid & 63;
    const int wid  = tid >> 6;       // 0..7
    const int wm   = wid >> 2;       // 0..1  (M half of tile)
    const int wn   = wid & 3;        // 0..3  (N quarter)
    const int kh   = lane >> 4;      // 0..3
    const int lr   = lane & 15;

    // XCD-bijective swizzle (grid % 8 == 0 guaranteed by host gate)
    int bid = blockIdx.x;
    const int nwg = gridDim.x;
    if ((nwg & 7) == 0) { const int cpx = nwg >> 3; bid = (bid & 7) * cpx + (bid >> 3); }
    const int nbn = N / BN;
    const int tm = bid / nbn, tn = bid % nbn;
    const int arow0 = tm * BM;
    const int brow0 = tn * BN;
    const int NT = K / BK;

    // ---- A: 8 running per-lane pointers (group = 16-row block) ----
    // addr = Xqt + group*(16K) + C*256 + lr*16, C = 8t + kh + 4ks
    const size_t GSTR = (size_t)16 * K;
    const int gbase = (arow0 >> 4) + wm * 8;     // halves: +0..3 lo, +4..7 hi
    const signed char* pA[8];
    #pragma unroll
    for (int mh = 0; mh < 8; ++mh)
        pA[mh] = Xqt + (size_t)(gbase + mh) * GSTR + kh * 256 + lr * 16;

    // ---- B LDS read byte-offsets (buffer 0; toggle via OR tb) ----
    unsigned boff[2][2];
    #pragma unroll
    for (int ks = 0; ks < 2; ++ks) {
        const int c = kh + ks * 4;
        #pragma unroll
        for (int nf = 0; nf < 2; ++nf) {
            const int row = wn * 64 + nf * 16 + lr;               // b-lo row
            boff[ks][nf] = (unsigned)(row * 128 + ((c ^ (row & 7)) << 4));
        }
    }
    // b-hi = +4096 bytes (row+32: same &7 -> same swizzle).

    // ---- B stage streams (r12 pattern) ----
    const int r0 = tid >> 3;
    const int c0 = (((tid & 7) ^ (r0 & 7)) << 4);
    const int ci1 = 512 + tid;
    const int r1 = ci1 >> 3;
    const int c1 = (((ci1 & 7) ^ (r1 & 7)) << 4);

    const signed char* bsrc[2][2];
    unsigned bdst[2][2];
    #pragma unroll
    for (int hh = 0; hh < 2; ++hh) {
        bsrc[hh][0] = Qq + (size_t)(brow0 + hh * 128 + r0) * K + BK + c0;   // B(t+1)
        bsrc[hh][1] = Qq + (size_t)(brow0 + hh * 128 + r1) * K + BK + c1;
        bdst[hh][0] = (unsigned)(hh * 16384 + tid * 16);
        bdst[hh][1] = (unsigned)(hh * 16384 + ci1 * 16);
    }

    // ---- prologue: stage B(0) -> buf0; load aC0/aC1 (tile 0) ----
    #pragma unroll
    for (int hh = 0; hh < 2; ++hh) {
        const signed char* gb0 = Qq + (size_t)(brow0 + hh * 128 + r0) * K + c0;
        const signed char* gb1 = Qq + (size_t)(brow0 + hh * 128 + r1) * K + c1;
        __builtin_amdgcn_global_load_lds(GLOBAL_CAST(gb0), LDS_CAST(lds + bdst[hh][0]), 16, 0, 0);
        __builtin_amdgcn_global_load_lds(GLOBAL_CAST(gb1), LDS_CAST(lds + bdst[hh][1]), 16, 0, 0);
    }
    i32x4 aC0[4], aC1[4];
    #pragma unroll
    for (int mf = 0; mf < 4; ++mf) aC0[mf] = *(const i32x4*)(pA[mf]);
    #pragma unroll
    for (int mf = 0; mf < 4; ++mf) aC1[mf] = *(const i32x4*)(pA[mf] + 1024);

    asm volatile("s_waitcnt vmcnt(0)" ::: "memory");   // order-independent drain
    __builtin_amdgcn_sched_barrier(0);
    __builtin_amdgcn_s_barrier();

    i32x4 acc[8][4] = {};

    #define MFMA8(AV, BV, AI, BJ)                                             \
        _Pragma("unroll")                                                     \
        for (int mf = 0; mf < 4; ++mf)                                        \
            _Pragma("unroll")                                                 \
            for (int nf = 0; nf < 2; ++nf)                                    \
                acc[(AI) + mf][(BJ) + nf] =                                   \
                    __builtin_amdgcn_mfma_i32_16x16x64_i8(                    \
                        AV[mf], BV[nf], acc[(AI) + mf][(BJ) + nf], 0, 0, 0);

    for (int t = 0; t < NT; ++t) {
        const unsigned tb = (unsigned)(t & 1) << 15;
        const unsigned ta = tb ^ 0x8000u;
        const bool doS = (t < NT - 1);

        i32x4 aH[4], bL[2], bH[2];

        // ================= ks = 0 =================
        #pragma unroll
        for (int mf = 0; mf < 4; ++mf) aH[mf] = *(const i32x4*)(pA[4 + mf]);
        if (doS) {
            #pragma unroll
            for (int hh = 0; hh < 2; ++hh) {
                __builtin_amdgcn_global_load_lds(GLOBAL_CAST(bsrc[hh][0]), LDS_CAST(lds + (ta | bdst[hh][0])), 16, 0, 0);
                __builtin_amdgcn_global_load_lds(GLOBAL_CAST(bsrc[hh][1]), LDS_CAST(lds + (ta | bdst[hh][1])), 16, 0, 0);
            }
        }
        #pragma unroll
        for (int nf = 0; nf < 2; ++nf) {
            bL[nf] = *(const i32x4*)(lds + (tb | boff[0][nf]));
            bH[nf] = *(const i32x4*)(lds + (tb | boff[0][nf]) + 4096);
        }
        __builtin_amdgcn_s_setprio(1);
        MFMA8(aC0, bL, 0, 0)
        MFMA8(aC0, bH, 0, 2)
        MFMA8(aH,  bH, 4, 2)
        MFMA8(aH,  bL, 4, 0)
        __builtin_amdgcn_s_setprio(0);
        if (doS) {
            #pragma unroll
            for (int mf = 0; mf < 4; ++mf) aC0[mf] = *(const i32x4*)(pA[mf] + 2048);
        }

        // ================= ks = 1 =================
        #pragma unroll
        for (int mf = 0; mf < 4; ++mf) aH[mf] = *(const i32x4*)(pA[4 + mf] + 1024);
        #pragma unroll
        for (int nf = 0; nf < 2; ++nf) {
            bL[nf] = *(const i32x4*)(lds + (tb | boff[1][nf]));
            bH[nf] = *(const i32x4*)(lds + (tb | boff[1][nf]) + 4096);
        }
        __builtin_amdgcn_s_setprio(1);
        MFMA8(aC1, bL, 0, 0)
        MFMA8(aC1, bH, 0, 2)
        __builtin_amdgcn_s_setprio(0);
        if (doS) {
            #pragma unroll
            for (int mf = 0; mf < 4; ++mf) aC1[mf] = *(const i32x4*)(pA[mf] + 3072);
        }
        __builtin_amdgcn_s_setprio(1);
        MFMA8(aH, bH, 4, 2)
        MFMA8(aH, bL, 4, 0)
        __builtin_amdgcn_s_setprio(0);

        // advance streams
        #pragma unroll
        for (int mh = 0; mh < 8; ++mh) pA[mh] += 2048;
        #pragma unroll
        for (int hh = 0; hh < 2; ++hh) { bsrc[hh][0] += BK; bsrc[hh][1] += BK; }

        asm volatile("s_waitcnt vmcnt(0)" ::: "memory");
        __builtin_amdgcn_sched_barrier(0);
        __builtin_amdgcn_s_barrier();
    }
    #undef MFMA8

    // epilogue: out = sx[m]*scale[n]*acc + bias[n]
    // D layout: col = lane&15, row = (lane>>4)*4 + r
    float sxv[32];
    #pragma unroll
    for (int mf = 0; mf < 8; ++mf)
        #pragma unroll
        for (int r = 0; r < 4; ++r)
            sxv[mf * 4 + r] = sx[arow0 + wm * 128 + mf * 16 + kh * 4 + r];

    #pragma unroll
    for (int nf = 0; nf < 4; ++nf) {
        const int gn = brow0 + wn * 64 + nf * 16 + lr;
        const float sc = scale[gn];
        const float bs = bias[gn];
        #pragma unroll
        for (int mf = 0; mf < 8; ++mf) {
            const size_t gm = (size_t)arow0 + wm * 128 + mf * 16 + kh * 4;
            #pragma unroll
            for (int r = 0; r < 4; ++r)
                out[(gm + r) * (size_t)N + gn] =
                    (float)acc[mf][nf][r] * (sxv[mf * 4 + r] * sc) + bs;
        }
    }
}

// ---------------------------------------------------------------------------
// Fallback: fp32 smem-tiled GEMM, quantize on the fly.
// ---------------------------------------------------------------------------
__global__ __launch_bounds__(256) void fb_gemm_kernel(
    const float* __restrict__ X, const float* __restrict__ W,
    const float* __restrict__ scale, const float* __restrict__ bias,
    float* __restrict__ out, int M, int N, int K)
{
    __shared__ float xs[16][16];
    __shared__ float qs[16][17];
    const int tx = threadIdx.x & 15, ty = threadIdx.x >> 4;
    const int m = blockIdx.y * 16 + ty;
    const int n = blockIdx.x * 16 + tx;
    const int nrow = blockIdx.x * 16 + ty;
    const int mL = min(m, M - 1);
    const int nrowL = min(nrow, N - 1);
    const float thr = scale[nrowL] * 0.75f;
    float acc = 0.f;
    for (int k0 = 0; k0 < K; k0 += 16) {
        xs[ty][tx] = X[(size_t)mL * K + k0 + tx];
        const float w = W[(size_t)nrowL * K + k0 + tx];
        qs[ty][tx] = (w >= thr) ? 1.f : ((w <= -thr) ? -1.f : 0.f);
        __syncthreads();
        #pragma unroll
        for (int kk = 0; kk < 16; ++kk) acc += xs[ty][kk] * qs[tx][kk];
        __syncthreads();
    }
    if (m < M && n < N) out[(size_t)m * N + n] = scale[n] * acc + bias[n];
}

// ---------------------------------------------------------------------------
extern "C" void kernel_launch(void* const* d_in, const int* in_sizes, int n_in,
                              void* d_out, int out_size, void* d_ws, size_t ws_size,
                              hipStream_t stream)
{
    const float* x    = (const float*)d_in[0];
    const float* w    = (const float*)d_in[1];
    const float* bias = (const float*)d_in[2];
    float* out = (float*)d_out;

    const int N = in_sizes[2];             // OUT
    const int K = in_sizes[1] / N;         // IN
    const int M = in_sizes[0] / K;         // B

    const size_t scOff = 0;
    const size_t sxOff = (scOff + (size_t)N * 4 + 255) & ~(size_t)255;
    const size_t qOff  = (sxOff + (size_t)M * 4 + 255) & ~(size_t)255;
    const size_t xqOff = (qOff + (size_t)N * K + 255) & ~(size_t)255;
    const size_t need  = xqOff + (size_t)M * K;

    float* scale = (float*)((char*)d_ws + scOff);

    const bool fast = (ws_size >= need) &&
                      (M % BM == 0) && (N % BN == 0) && (K % BK == 0) &&
                      (K % 256 == 0) && (K / BK >= 4) &&
                      (((M / BM) * (N / BN)) % 8 == 0);

    if (fast) {
        float* sx        = (float*)((char*)d_ws + sxOff);
        signed char* q   = (signed char*)((char*)d_ws + qOff);
        signed char* xqt = (signed char*)((char*)d_ws + xqOff);

        scale_quant_kernel<<<N, 256, 0, stream>>>(w, scale, q, K);
        x_quant_tiled_kernel<<<M / 16, 256, 0, stream>>>(x, sx, xqt, K);

        const int grid = (M / BM) * (N / BN);
        gemm256_i8_kernel<<<grid, 512, 0, stream>>>(xqt, q, sx, scale, bias, out, M, N, K);
    } else {
        scale_quant_kernel<<<N, 256, 0, stream>>>(w, scale, nullptr, K);
        dim3 g((N + 15) / 16, (M + 15) / 16);
        fb_gemm_kernel<<<g, 256, 0, stream>>>(x, w, scale, bias, out, M, N, K);
    }
}

// Round 16
// 205.083 us; speedup vs baseline: 1.2832x; 1.2832x over previous
//
#include <hip/hip_runtime.h>
#include <hip/hip_bf16.h>

typedef __attribute__((ext_vector_type(4))) int i32x4;

#define GLOBAL_CAST(p) (const __attribute__((address_space(1))) void*)(p)
#define LDS_CAST(p)    (__attribute__((address_space(3))) void*)(p)

// ---------------------------------------------------------------------------
// Kernel 1: per-row scale = max(mean(|w|), eps); q = ternary(w) as i8.
// ---------------------------------------------------------------------------
__global__ __launch_bounds__(256) void scale_quant_kernel(
    const float* __restrict__ w, float* __restrict__ scale,
    signed char* __restrict__ q, int K)
{
    const int row = blockIdx.x;
    const int tid = threadIdx.x;
    const float* wrow = w + (size_t)row * K;

    float s = 0.f;
    const int nvec = K >> 2;
    const float4* wv = (const float4*)wrow;
    for (int i = tid; i < nvec; i += blockDim.x) {
        float4 v = wv[i];
        s += fabsf(v.x) + fabsf(v.y) + fabsf(v.z) + fabsf(v.w);
    }
    #pragma unroll
    for (int off = 32; off > 0; off >>= 1) s += __shfl_down(s, off);

    __shared__ float red[4];
    const int lane = tid & 63, wid = tid >> 6;
    if (lane == 0) red[wid] = s;
    __syncthreads();
    const float total = red[0] + red[1] + red[2] + red[3];
    const float sc = fmaxf(total / (float)K, 1e-6f);
    const float thr = sc * 0.75f;
    if (tid == 0) scale[row] = sc;

    if (q != nullptr) {
        char4* qv = (char4*)(q + (size_t)row * K);
        for (int i = tid; i < nvec; i += blockDim.x) {
            float4 v = wv[i];
            char4 o;
            o.x = (v.x >= thr) ? 1 : ((v.x <= -thr) ? -1 : 0);
            o.y = (v.y >= thr) ? 1 : ((v.y <= -thr) ? -1 : 0);
            o.z = (v.z >= thr) ? 1 : ((v.z <= -thr) ? -1 : 0);
            o.w = (v.w >= thr) ? 1 : ((v.w <= -thr) ? -1 : 0);
            qv[i] = o;
        }
    }
}

// ---------------------------------------------------------------------------
// Kernel 2: per-row symmetric i8 quantization of x (row-major, r12 version).
// ---------------------------------------------------------------------------
__global__ __launch_bounds__(256) void x_quant_kernel(
    const float* __restrict__ x, float* __restrict__ sx,
    signed char* __restrict__ xq, int K)
{
    const int row = blockIdx.x;
    const int tid = threadIdx.x;
    const float4* xv = (const float4*)(x + (size_t)row * K);
    const int nvec = K >> 2;

    float am = 0.f;
    for (int i = tid; i < nvec; i += blockDim.x) {
        float4 v = xv[i];
        am = fmaxf(am, fmaxf(fmaxf(fabsf(v.x), fabsf(v.y)), fmaxf(fabsf(v.z), fabsf(v.w))));
    }
    #pragma unroll
    for (int off = 32; off > 0; off >>= 1) am = fmaxf(am, __shfl_down(am, off));

    __shared__ float red[4];
    const int lane = tid & 63, wid = tid >> 6;
    if (lane == 0) red[wid] = am;
    __syncthreads();
    const float amax = fmaxf(fmaxf(red[0], red[1]), fmaxf(red[2], red[3]));
    const float inv = (amax > 0.f) ? (127.f / amax) : 0.f;
    if (tid == 0) sx[row] = amax * (1.f / 127.f);

    char4* qv = (char4*)(xq + (size_t)row * K);
    for (int i = tid; i < nvec; i += blockDim.x) {
        float4 v = xv[i];
        char4 o;
        o.x = (signed char)__float2int_rn(v.x * inv);
        o.y = (signed char)__float2int_rn(v.y * inv);
        o.z = (signed char)__float2int_rn(v.z * inv);
        o.w = (signed char)__float2int_rn(v.w * inv);
        qv[i] = o;
    }
}

// ---------------------------------------------------------------------------
// Kernel 3: 128x128 i8 GEMM, 2 BLOCKS/CU (64 KiB LDS), r12 inner schedule.
//   out[m][n] = sx[m]*scale[n] * (sum_k xq[m][k]*q[n][k]) + bias[n]
// 256 thr = 4 waves (2M x 2N); per-wave 64x64 out = acc[4][4] i32x4 (64 reg).
// Rationale: r12's 1-block/CU structure idles the whole CU at the tile-end
// drain+barrier -> serialized MFMA+LDS floor. Two co-resident blocks =
// independent barrier domains; one block's drain overlaps the other's
// MFMA+ds_read (m114). r8's bf16 version lost to traffic (96MB working set
// thrashed L3); in i8 A+B = 48MB << 256MB L3, so panel re-reads are absorbed.
// LDS 64 KiB: 2 dbuf x {A 128x128i8 | B 128x128i8} (16 KB each; row 128 B,
// proven-0-conflict chunk swizzle: slot s of row r holds global chunk s^(r&7);
// dest LINEAR, source pre-swizzled -- rule-21-safe).
// Per K-tile t (reads from buf tb, DMA writes ONLY into buf ta):
//   sec A: stage A(t+1)->ta | rd b(8), a-lo(4) | MFMA q0 q1 |
//          stage B(t+1)->ta | mid barrier
//   sec B: rd a-hi(4) | MFMA q2 q3 | vmcnt(0) | sched_barrier | s_barrier
// Prologue vmcnt(0) (order-independent; r14 race lesson).
// i32 accumulation exact; error = X-quant only.
// ---------------------------------------------------------------------------
#define BM 128
#define BN 128
#define BK 128

__global__ __launch_bounds__(256, 2) void gemm128_i8_kernel(
    const signed char* __restrict__ Xq,   // [M][K] i8
    const signed char* __restrict__ Qq,   // [N][K] i8
    const float* __restrict__ sx,         // [M]
    const float* __restrict__ scale,      // [N]
    const float* __restrict__ bias,       // [N]
    float* __restrict__ out, int M, int N, int K)
{
    __shared__ __align__(16) char lds[65536];

    const int tid  = threadIdx.x;
    const int lane = tid & 63;
    const int wid  = tid >> 6;       // 0..3
    const int wm   = wid >> 1;       // 0..1  (M half of tile)
    const int wn   = wid & 1;        // 0..1  (N half)
    const int kh   = lane >> 4;      // 0..3
    const int lr   = lane & 15;

    // XCD-bijective swizzle (grid % 8 == 0 guaranteed by host gate)
    int bid = blockIdx.x;
    const int nwg = gridDim.x;
    if ((nwg & 7) == 0) { const int cpx = nwg >> 3; bid = (bid & 7) * cpx + (bid >> 3); }
    const int nbn = N / BN;
    const int tm = bid / nbn, tn = bid % nbn;
    const int arow0 = tm * BM;
    const int brow0 = tn * BN;
    const int NT = K / BK;

    // ---- LDS read byte-offsets (buffer 0; toggle via OR tb) ----
    // chunk = kh + 4*ks; slot = chunk ^ (row&7); row stride 128 B.
    unsigned aoff[2][4], boff[2][4];
    #pragma unroll
    for (int ks = 0; ks < 2; ++ks) {
        const int c = kh + ks * 4;
        #pragma unroll
        for (int mf = 0; mf < 4; ++mf) {
            const int row = wm * 64 + mf * 16 + lr;
            aoff[ks][mf] = (unsigned)(row * 128 + ((c ^ (row & 7)) << 4));
        }
        #pragma unroll
        for (int nf = 0; nf < 4; ++nf) {
            const int row = wn * 64 + nf * 16 + lr;
            boff[ks][nf] = (unsigned)(0x4000 + row * 128 + ((c ^ (row & 7)) << 4));
        }
    }

    // ---- staging: 1024 chunks per 128x128 i8 tile; 4/thread for A, 4 for B --
    int rj[4]; unsigned dstj[4]; int cj[4];
    #pragma unroll
    for (int j = 0; j < 4; ++j) {
        const int ci = tid + j * 256;
        rj[j] = ci >> 3;
        cj[j] = (((ci & 7) ^ (rj[j] & 7)) << 4);   // i8 elems (16/chunk)
        dstj[j] = (unsigned)(ci * 16);
    }

    const signed char* asrc[4];
    const signed char* bsrc[4];
    #pragma unroll
    for (int j = 0; j < 4; ++j) {
        asrc[j] = Xq + (size_t)(arow0 + rj[j]) * K + BK + cj[j];   // A(t+1)
        bsrc[j] = Qq + (size_t)(brow0 + rj[j]) * K + BK + cj[j];   // B(t+1)
    }

    // ---- prologue: stage tile 0 {A,B} into buffer 0 ----
    #pragma unroll
    for (int j = 0; j < 4; ++j) {
        const signed char* ga = Xq + (size_t)(arow0 + rj[j]) * K + cj[j];
        const signed char* gb = Qq + (size_t)(brow0 + rj[j]) * K + cj[j];
        __builtin_amdgcn_global_load_lds(GLOBAL_CAST(ga), LDS_CAST(lds + dstj[j]), 16, 0, 0);
        __builtin_amdgcn_global_load_lds(GLOBAL_CAST(gb), LDS_CAST(lds + (dstj[j] | 0x4000u)), 16, 0, 0);
    }
    asm volatile("s_waitcnt vmcnt(0)" ::: "memory");
    __builtin_amdgcn_sched_barrier(0);
    __builtin_amdgcn_s_barrier();

    i32x4 acc[4][4] = {};
    i32x4 a[2][2];        // time-shared between M halves
    i32x4 b[2][4];

    #define RDA(ks, mf) (*(const i32x4*)(lds + (tb | aoff[ks][mf])))
    #define RDB(ks, nf) (*(const i32x4*)(lds + (tb | boff[ks][nf])))
    #define MFMA8(AI, BJ)                                                     \
        _Pragma("unroll")                                                     \
        for (int ks = 0; ks < 2; ++ks)                                        \
            _Pragma("unroll")                                                 \
            for (int mh = 0; mh < 2; ++mh)                                    \
                _Pragma("unroll")                                             \
                for (int nh = 0; nh < 2; ++nh)                                \
                    acc[(AI) + mh][(BJ) + nh] =                               \
                        __builtin_amdgcn_mfma_i32_16x16x64_i8(                \
                            a[ks][mh], b[ks][(BJ) + nh],                      \
                            acc[(AI) + mh][(BJ) + nh], 0, 0, 0);

    for (int t = 0; t < NT; ++t) {
        const unsigned tb = (unsigned)(t & 1) << 15;
        const unsigned ta = tb ^ 0x8000u;
        const bool doS = (t < NT - 1);

        // ================= section A =================
        if (doS) {
            #pragma unroll
            for (int j = 0; j < 4; ++j)
                __builtin_amdgcn_global_load_lds(GLOBAL_CAST(asrc[j]), LDS_CAST(lds + (ta | dstj[j])), 16, 0, 0);
        }
        #pragma unroll
        for (int ks = 0; ks < 2; ++ks) {
            #pragma unroll
            for (int nf = 0; nf < 4; ++nf) b[ks][nf] = RDB(ks, nf);
            #pragma unroll
            for (int mh = 0; mh < 2; ++mh) a[ks][mh] = RDA(ks, mh);      // a-lo
        }
        __builtin_amdgcn_s_setprio(1);
        MFMA8(0, 0)
        MFMA8(0, 2)
        __builtin_amdgcn_s_setprio(0);

        if (doS) {
            #pragma unroll
            for (int j = 0; j < 4; ++j)
                __builtin_amdgcn_global_load_lds(GLOBAL_CAST(bsrc[j]), LDS_CAST(lds + (ta | dstj[j] | 0x4000u)), 16, 0, 0);
        }
        __builtin_amdgcn_s_barrier();

        // ================= section B =================
        #pragma unroll
        for (int ks = 0; ks < 2; ++ks)
            #pragma unroll
            for (int mh = 0; mh < 2; ++mh) a[ks][mh] = RDA(ks, 2 + mh);  // a-hi
        __builtin_amdgcn_s_setprio(1);
        MFMA8(2, 2)
        MFMA8(2, 0)
        __builtin_amdgcn_s_setprio(0);

        // advance stage streams (BK i8 = 128 B)
        #pragma unroll
        for (int j = 0; j < 4; ++j) { asrc[j] += BK; bsrc[j] += BK; }

        asm volatile("s_waitcnt vmcnt(0)" ::: "memory");
        __builtin_amdgcn_sched_barrier(0);
        __builtin_amdgcn_s_barrier();
    }
    #undef RDA
    #undef RDB
    #undef MFMA8

    // epilogue: out = sx[m]*scale[n]*acc + bias[n]
    // D layout: col = lane&15, row = (lane>>4)*4 + r
    float sxv[16];
    #pragma unroll
    for (int mf = 0; mf < 4; ++mf)
        #pragma unroll
        for (int r = 0; r < 4; ++r)
            sxv[mf * 4 + r] = sx[arow0 + wm * 64 + mf * 16 + kh * 4 + r];

    #pragma unroll
    for (int nf = 0; nf < 4; ++nf) {
        const int gn = brow0 + wn * 64 + nf * 16 + lr;
        const float sc = scale[gn];
        const float bs = bias[gn];
        #pragma unroll
        for (int mf = 0; mf < 4; ++mf) {
            const size_t gm = (size_t)arow0 + wm * 64 + mf * 16 + kh * 4;
            #pragma unroll
            for (int r = 0; r < 4; ++r)
                out[(gm + r) * (size_t)N + gn] =
                    (float)acc[mf][nf][r] * (sxv[mf * 4 + r] * sc) + bs;
        }
    }
}

// ---------------------------------------------------------------------------
// Fallback: fp32 smem-tiled GEMM, quantize on the fly.
// ---------------------------------------------------------------------------
__global__ __launch_bounds__(256) void fb_gemm_kernel(
    const float* __restrict__ X, const float* __restrict__ W,
    const float* __restrict__ scale, const float* __restrict__ bias,
    float* __restrict__ out, int M, int N, int K)
{
    __shared__ float xs[16][16];
    __shared__ float qs[16][17];
    const int tx = threadIdx.x & 15, ty = threadIdx.x >> 4;
    const int m = blockIdx.y * 16 + ty;
    const int n = blockIdx.x * 16 + tx;
    const int nrow = blockIdx.x * 16 + ty;
    const int mL = min(m, M - 1);
    const int nrowL = min(nrow, N - 1);
    const float thr = scale[nrowL] * 0.75f;
    float acc = 0.f;
    for (int k0 = 0; k0 < K; k0 += 16) {
        xs[ty][tx] = X[(size_t)mL * K + k0 + tx];
        const float w = W[(size_t)nrowL * K + k0 + tx];
        qs[ty][tx] = (w >= thr) ? 1.f : ((w <= -thr) ? -1.f : 0.f);
        __syncthreads();
        #pragma unroll
        for (int kk = 0; kk < 16; ++kk) acc += xs[ty][kk] * qs[tx][kk];
        __syncthreads();
    }
    if (m < M && n < N) out[(size_t)m * N + n] = scale[n] * acc + bias[n];
}

// ---------------------------------------------------------------------------
extern "C" void kernel_launch(void* const* d_in, const int* in_sizes, int n_in,
                              void* d_out, int out_size, void* d_ws, size_t ws_size,
                              hipStream_t stream)
{
    const float* x    = (const float*)d_in[0];
    const float* w    = (const float*)d_in[1];
    const float* bias = (const float*)d_in[2];
    float* out = (float*)d_out;

    const int N = in_sizes[2];             // OUT
    const int K = in_sizes[1] / N;         // IN
    const int M = in_sizes[0] / K;         // B

    const size_t scOff = 0;
    const size_t sxOff = (scOff + (size_t)N * 4 + 255) & ~(size_t)255;
    const size_t qOff  = (sxOff + (size_t)M * 4 + 255) & ~(size_t)255;
    const size_t xqOff = (qOff + (size_t)N * K + 255) & ~(size_t)255;
    const size_t need  = xqOff + (size_t)M * K;

    float* scale = (float*)((char*)d_ws + scOff);

    const bool fast = (ws_size >= need) &&
                      (M % BM == 0) && (N % BN == 0) && (K % BK == 0) &&
                      ((K & 3) == 0) && (K / BK >= 2) &&
                      (((M / BM) * (N / BN)) % 8 == 0);

    if (fast) {
        float* sx        = (float*)((char*)d_ws + sxOff);
        signed char* q   = (signed char*)((char*)d_ws + qOff);
        signed char* xq  = (signed char*)((char*)d_ws + xqOff);

        scale_quant_kernel<<<N, 256, 0, stream>>>(w, scale, q, K);
        x_quant_kernel<<<M, 256, 0, stream>>>(x, sx, xq, K);

        const int grid = (M / BM) * (N / BN);
        gemm128_i8_kernel<<<grid, 256, 0, stream>>>(xq, q, sx, scale, bias, out, M, N, K);
    } else {
        scale_quant_kernel<<<N, 256, 0, stream>>>(w, scale, nullptr, K);
        dim3 g((N + 15) / 16, (M + 15) / 16);
        fb_gemm_kernel<<<g, 256, 0, stream>>>(x, w, scale, bias, out, M, N, K);
    }
}

// Round 17
// 179.524 us; speedup vs baseline: 1.4658x; 1.1424x over previous
//
#include <hip/hip_runtime.h>
#include <hip/hip_bf16.h>

typedef __attribute__((ext_vector_type(4))) int i32x4;

#define GLOBAL_CAST(p) (const __attribute__((address_space(1))) void*)(p)
#define LDS_CAST(p)    (__attribute__((address_space(3))) void*)(p)

// ---------------------------------------------------------------------------
// Kernel 1: per-row scale = max(mean(|w|), eps); q = ternary(w) as i8.
// Single-read when the row fits in registers (K <= 4096): 4 float4/thread.
// ---------------------------------------------------------------------------
__global__ __launch_bounds__(256) void scale_quant_kernel(
    const float* __restrict__ w, float* __restrict__ scale,
    signed char* __restrict__ q, int K)
{
    const int row = blockIdx.x;
    const int tid = threadIdx.x;
    const float* wrow = w + (size_t)row * K;
    const int nvec = K >> 2;
    const float4* wv = (const float4*)wrow;

    __shared__ float red[4];
    const int lane = tid & 63, wid = tid >> 6;

    if (nvec == 1024) {                      // K == 4096 fast path: read once
        float4 v[4];
        float s = 0.f;
        #pragma unroll
        for (int j = 0; j < 4; ++j) {
            v[j] = wv[tid + j * 256];
            s += fabsf(v[j].x) + fabsf(v[j].y) + fabsf(v[j].z) + fabsf(v[j].w);
        }
        #pragma unroll
        for (int off = 32; off > 0; off >>= 1) s += __shfl_down(s, off);
        if (lane == 0) red[wid] = s;
        __syncthreads();
        const float total = red[0] + red[1] + red[2] + red[3];
        const float sc = fmaxf(total / (float)K, 1e-6f);
        const float thr = sc * 0.75f;
        if (tid == 0) scale[row] = sc;
        if (q != nullptr) {
            char4* qv = (char4*)(q + (size_t)row * K);
            #pragma unroll
            for (int j = 0; j < 4; ++j) {
                char4 o;
                o.x = (v[j].x >= thr) ? 1 : ((v[j].x <= -thr) ? -1 : 0);
                o.y = (v[j].y >= thr) ? 1 : ((v[j].y <= -thr) ? -1 : 0);
                o.z = (v[j].z >= thr) ? 1 : ((v[j].z <= -thr) ? -1 : 0);
                o.w = (v[j].w >= thr) ? 1 : ((v[j].w <= -thr) ? -1 : 0);
                qv[tid + j * 256] = o;
            }
        }
        return;
    }

    // generic two-pass path
    float s = 0.f;
    for (int i = tid; i < nvec; i += blockDim.x) {
        float4 v = wv[i];
        s += fabsf(v.x) + fabsf(v.y) + fabsf(v.z) + fabsf(v.w);
    }
    #pragma unroll
    for (int off = 32; off > 0; off >>= 1) s += __shfl_down(s, off);
    if (lane == 0) red[wid] = s;
    __syncthreads();
    const float total = red[0] + red[1] + red[2] + red[3];
    const float sc = fmaxf(total / (float)K, 1e-6f);
    const float thr = sc * 0.75f;
    if (tid == 0) scale[row] = sc;
    if (q != nullptr) {
        char4* qv = (char4*)(q + (size_t)row * K);
        for (int i = tid; i < nvec; i += blockDim.x) {
            float4 v = wv[i];
            char4 o;
            o.x = (v.x >= thr) ? 1 : ((v.x <= -thr) ? -1 : 0);
            o.y = (v.y >= thr) ? 1 : ((v.y <= -thr) ? -1 : 0);
            o.z = (v.z >= thr) ? 1 : ((v.z <= -thr) ? -1 : 0);
            o.w = (v.w >= thr) ? 1 : ((v.w <= -thr) ? -1 : 0);
            qv[i] = o;
        }
    }
}

// ---------------------------------------------------------------------------
// Kernel 2: per-row symmetric i8 quantization of x; single-read at K==4096.
// ---------------------------------------------------------------------------
__global__ __launch_bounds__(256) void x_quant_kernel(
    const float* __restrict__ x, float* __restrict__ sx,
    signed char* __restrict__ xq, int K)
{
    const int row = blockIdx.x;
    const int tid = threadIdx.x;
    const float4* xv = (const float4*)(x + (size_t)row * K);
    const int nvec = K >> 2;

    __shared__ float red[4];
    const int lane = tid & 63, wid = tid >> 6;

    if (nvec == 1024) {                      // K == 4096 fast path: read once
        float4 v[4];
        float am = 0.f;
        #pragma unroll
        for (int j = 0; j < 4; ++j) {
            v[j] = xv[tid + j * 256];
            am = fmaxf(am, fmaxf(fmaxf(fabsf(v[j].x), fabsf(v[j].y)),
                                 fmaxf(fabsf(v[j].z), fabsf(v[j].w))));
        }
        #pragma unroll
        for (int off = 32; off > 0; off >>= 1) am = fmaxf(am, __shfl_down(am, off));
        if (lane == 0) red[wid] = am;
        __syncthreads();
        const float amax = fmaxf(fmaxf(red[0], red[1]), fmaxf(red[2], red[3]));
        const float inv = (amax > 0.f) ? (127.f / amax) : 0.f;
        if (tid == 0) sx[row] = amax * (1.f / 127.f);
        char4* qv = (char4*)(xq + (size_t)row * K);
        #pragma unroll
        for (int j = 0; j < 4; ++j) {
            char4 o;
            o.x = (signed char)__float2int_rn(v[j].x * inv);
            o.y = (signed char)__float2int_rn(v[j].y * inv);
            o.z = (signed char)__float2int_rn(v[j].z * inv);
            o.w = (signed char)__float2int_rn(v[j].w * inv);
            qv[tid + j * 256] = o;
        }
        return;
    }

    float am = 0.f;
    for (int i = tid; i < nvec; i += blockDim.x) {
        float4 v = xv[i];
        am = fmaxf(am, fmaxf(fmaxf(fabsf(v.x), fabsf(v.y)), fmaxf(fabsf(v.z), fabsf(v.w))));
    }
    #pragma unroll
    for (int off = 32; off > 0; off >>= 1) am = fmaxf(am, __shfl_down(am, off));
    if (lane == 0) red[wid] = am;
    __syncthreads();
    const float amax = fmaxf(fmaxf(red[0], red[1]), fmaxf(red[2], red[3]));
    const float inv = (amax > 0.f) ? (127.f / amax) : 0.f;
    if (tid == 0) sx[row] = amax * (1.f / 127.f);
    char4* qv = (char4*)(xq + (size_t)row * K);
    for (int i = tid; i < nvec; i += blockDim.x) {
        float4 v = xv[i];
        char4 o;
        o.x = (signed char)__float2int_rn(v.x * inv);
        o.y = (signed char)__float2int_rn(v.y * inv);
        o.z = (signed char)__float2int_rn(v.z * inv);
        o.w = (signed char)__float2int_rn(v.w * inv);
        qv[i] = o;
    }
}

// ---------------------------------------------------------------------------
// Kernel 3: 256x256 i8 GEMM (mfma_i32_16x16x64_i8), WAVE ANTI-PHASE.
//   out[m][n] = sx[m]*scale[n] * (sum_k xq[m][k]*q[n][k]) + bias[n]
// 512 thr = 8 waves (2M x 4N); per-wave 128x64 out = acc[8][4] i32x4.
// LDS 128 KiB: 2 dbuf x {A 256x128i8 | B 256x128i8}; r12 chunk swizzle
// (slot s of row r holds global chunk s^(r&7); dest LINEAR, source
// pre-swizzled; 0 conflicts measured).
// ANTI-PHASE: K-tile = 2 independent k-slices ks0/ks1 (disjoint LDS chunks;
// addr(ks) = addr(0) ^ (ks<<6) since chunk bits are XOR-disjoint from the
// swizzle). Waves 0-3 process ks0->ks1; waves 4-7 process ks1->ks0 (wave i
// lands on SIMD i%4, so each SIMD holds one wave of each order). At any
// instant ~half the waves MFMA while half ds_read -> LDS pipe and matrix
// pipe overlap instead of the measured fully-serial lockstep (4920 cyc =
// 2612 MFMA + 2304 LDS per K-tile). No mid barrier; per-phase reads feed
// per-phase MFMAs; tile-end vmcnt(0)+barrier unchanged (order-independent).
// i32 accumulation exact; error = X-quant only.
// ---------------------------------------------------------------------------
#define BM 256
#define BN 256
#define BK 128

__global__ __launch_bounds__(512, 2) void gemm256_i8_kernel(
    const signed char* __restrict__ Xq,   // [M][K] i8
    const signed char* __restrict__ Qq,   // [N][K] i8
    const float* __restrict__ sx,         // [M]
    const float* __restrict__ scale,      // [N]
    const float* __restrict__ bias,       // [N]
    float* __restrict__ out, int M, int N, int K)
{
    __shared__ __align__(16) char lds[131072];

    const int tid  = threadIdx.x;
    const int lane = tid & 63;
    const int wid  = tid >> 6;       // 0..7
    const int wm   = wid >> 2;       // 0..1  (M half of tile)
    const int wn   = wid & 3;        // 0..3  (N quarter)
    const int kh   = lane >> 4;      // 0..3
    const int lr   = lane & 15;
    const int grp  = wm;             // anti-phase group: one per SIMD pair

    // XCD-bijective swizzle (grid % 8 == 0 guaranteed by host gate)
    int bid = blockIdx.x;
    const int nwg = gridDim.x;
    if ((nwg & 7) == 0) { const int cpx = nwg >> 3; bid = (bid & 7) * cpx + (bid >> 3); }
    const int nbn = N / BN;
    const int tm = bid / nbn, tn = bid % nbn;
    const int arow0 = tm * BM;
    const int brow0 = tn * BN;
    const int NT = K / BK;

    // ---- LDS read byte-offsets for ks=0 (buffer toggle: |tb ; ks: ^(ks<<6)) --
    unsigned aoff[8], boff[4];
    #pragma unroll
    for (int mf = 0; mf < 8; ++mf) {
        const int row = wm * 128 + mf * 16 + lr;
        aoff[mf] = (unsigned)(row * 128 + ((kh ^ (row & 7)) << 4));
    }
    #pragma unroll
    for (int nf = 0; nf < 4; ++nf) {
        const int row = wn * 64 + nf * 16 + lr;
        boff[nf] = (unsigned)(32768 + row * 128 + ((kh ^ (row & 7)) << 4));
    }

    // ---- stage streams: running global pointers + fixed LDS dest offs ----
    const int r0 = tid >> 3;
    const int c0 = (((tid & 7) ^ (r0 & 7)) << 4);
    const int ci1 = 512 + tid;
    const int r1 = ci1 >> 3;
    const int c1 = (((ci1 & 7) ^ (r1 & 7)) << 4);

    const signed char* asrc[2][2];
    const signed char* bsrc[2][2];
    unsigned adst[2][2], bdst[2][2];
    #pragma unroll
    for (int hh = 0; hh < 2; ++hh) {
        asrc[hh][0] = Xq + (size_t)(arow0 + hh * 128 + r0) * K + BK + c0;   // A(t+1)
        asrc[hh][1] = Xq + (size_t)(arow0 + hh * 128 + r1) * K + BK + c1;
        bsrc[hh][0] = Qq + (size_t)(brow0 + hh * 128 + r0) * K + BK + c0;   // B(t+1)
        bsrc[hh][1] = Qq + (size_t)(brow0 + hh * 128 + r1) * K + BK + c1;
        adst[hh][0] = (unsigned)(hh * 16384 + tid * 16);
        adst[hh][1] = (unsigned)(hh * 16384 + ci1 * 16);
        bdst[hh][0] = (unsigned)(32768 + hh * 16384 + tid * 16);
        bdst[hh][1] = (unsigned)(32768 + hh * 16384 + ci1 * 16);
    }

    // ---- prologue: stage tile 0 {A0,A1,B0,B1} into buffer 0 ----
    #pragma unroll
    for (int hh = 0; hh < 2; ++hh) {
        const int rowA = arow0 + hh * 128, rowB = brow0 + hh * 128;
        const signed char* ga0 = Xq + (size_t)(rowA + r0) * K + c0;
        const signed char* ga1 = Xq + (size_t)(rowA + r1) * K + c1;
        const signed char* gb0 = Qq + (size_t)(rowB + r0) * K + c0;
        const signed char* gb1 = Qq + (size_t)(rowB + r1) * K + c1;
        __builtin_amdgcn_global_load_lds(GLOBAL_CAST(ga0), LDS_CAST(lds + adst[hh][0]), 16, 0, 0);
        __builtin_amdgcn_global_load_lds(GLOBAL_CAST(ga1), LDS_CAST(lds + adst[hh][1]), 16, 0, 0);
        __builtin_amdgcn_global_load_lds(GLOBAL_CAST(gb0), LDS_CAST(lds + bdst[hh][0]), 16, 0, 0);
        __builtin_amdgcn_global_load_lds(GLOBAL_CAST(gb1), LDS_CAST(lds + bdst[hh][1]), 16, 0, 0);
    }
    asm volatile("s_waitcnt vmcnt(0)" ::: "memory");
    __builtin_amdgcn_sched_barrier(0);
    __builtin_amdgcn_s_barrier();

    i32x4 acc[8][4] = {};
    i32x4 a[8], b[4];

    #define PHASE(KX)                                                          \
        _Pragma("unroll")                                                      \
        for (int nf = 0; nf < 4; ++nf)                                         \
            b[nf] = *(const i32x4*)(lds + ((tb | boff[nf]) ^ (KX)));           \
        _Pragma("unroll")                                                      \
        for (int mf = 0; mf < 8; ++mf)                                         \
            a[mf] = *(const i32x4*)(lds + ((tb | aoff[mf]) ^ (KX)));           \
        __builtin_amdgcn_s_setprio(1);                                         \
        _Pragma("unroll")                                                      \
        for (int mf = 0; mf < 8; ++mf)                                         \
            _Pragma("unroll")                                                  \
            for (int nf = 0; nf < 4; ++nf)                                     \
                acc[mf][nf] = __builtin_amdgcn_mfma_i32_16x16x64_i8(           \
                    a[mf], b[nf], acc[mf][nf], 0, 0, 0);                       \
        __builtin_amdgcn_s_setprio(0);

    const unsigned kx0 = (unsigned)grp << 6;        // group's first slice
    const unsigned kx1 = kx0 ^ 64u;                 // group's second slice

    for (int t = 0; t < NT; ++t) {
        const unsigned tb = (unsigned)(t & 1) << 16;
        const unsigned ta = tb ^ 0x10000u;
        const bool doS = (t < NT - 1);

        // ---- phase 0: stage A(t+1); compute slice kx0 ----
        if (doS) {
            #pragma unroll
            for (int hh = 0; hh < 2; ++hh) {
                __builtin_amdgcn_global_load_lds(GLOBAL_CAST(asrc[hh][0]), LDS_CAST(lds + (ta | adst[hh][0])), 16, 0, 0);
                __builtin_amdgcn_global_load_lds(GLOBAL_CAST(asrc[hh][1]), LDS_CAST(lds + (ta | adst[hh][1])), 16, 0, 0);
            }
        }
        PHASE(kx0)

        // ---- phase 1: stage B(t+1); compute slice kx1 ----
        if (doS) {
            #pragma unroll
            for (int hh = 0; hh < 2; ++hh) {
                __builtin_amdgcn_global_load_lds(GLOBAL_CAST(bsrc[hh][0]), LDS_CAST(lds + (ta | bdst[hh][0])), 16, 0, 0);
                __builtin_amdgcn_global_load_lds(GLOBAL_CAST(bsrc[hh][1]), LDS_CAST(lds + (ta | bdst[hh][1])), 16, 0, 0);
            }
        }
        PHASE(kx1)

        // advance stage streams (BK i8 = 128 B)
        #pragma unroll
        for (int hh = 0; hh < 2; ++hh) {
            asrc[hh][0] += BK; asrc[hh][1] += BK;
            bsrc[hh][0] += BK; bsrc[hh][1] += BK;
        }
        asm volatile("s_waitcnt vmcnt(0)" ::: "memory");
        __builtin_amdgcn_sched_barrier(0);
        __builtin_amdgcn_s_barrier();
    }
    #undef PHASE

    // epilogue: out = sx[m]*scale[n]*acc + bias[n]
    // D layout: col = lane&15, row = (lane>>4)*4 + r
    float sxv[32];
    #pragma unroll
    for (int mf = 0; mf < 8; ++mf)
        #pragma unroll
        for (int r = 0; r < 4; ++r)
            sxv[mf * 4 + r] = sx[arow0 + wm * 128 + mf * 16 + kh * 4 + r];

    #pragma unroll
    for (int nf = 0; nf < 4; ++nf) {
        const int gn = brow0 + wn * 64 + nf * 16 + lr;
        const float sc = scale[gn];
        const float bs = bias[gn];
        #pragma unroll
        for (int mf = 0; mf < 8; ++mf) {
            const size_t gm = (size_t)arow0 + wm * 128 + mf * 16 + kh * 4;
            #pragma unroll
            for (int r = 0; r < 4; ++r)
                out[(gm + r) * (size_t)N + gn] =
                    (float)acc[mf][nf][r] * (sxv[mf * 4 + r] * sc) + bs;
        }
    }
}

// ---------------------------------------------------------------------------
// Fallback: fp32 smem-tiled GEMM, quantize on the fly.
// ---------------------------------------------------------------------------
__global__ __launch_bounds__(256) void fb_gemm_kernel(
    const float* __restrict__ X, const float* __restrict__ W,
    const float* __restrict__ scale, const float* __restrict__ bias,
    float* __restrict__ out, int M, int N, int K)
{
    __shared__ float xs[16][16];
    __shared__ float qs[16][17];
    const int tx = threadIdx.x & 15, ty = threadIdx.x >> 4;
    const int m = blockIdx.y * 16 + ty;
    const int n = blockIdx.x * 16 + tx;
    const int nrow = blockIdx.x * 16 + ty;
    const int mL = min(m, M - 1);
    const int nrowL = min(nrow, N - 1);
    const float thr = scale[nrowL] * 0.75f;
    float acc = 0.f;
    for (int k0 = 0; k0 < K; k0 += 16) {
        xs[ty][tx] = X[(size_t)mL * K + k0 + tx];
        const float w = W[(size_t)nrowL * K + k0 + tx];
        qs[ty][tx] = (w >= thr) ? 1.f : ((w <= -thr) ? -1.f : 0.f);
        __syncthreads();
        #pragma unroll
        for (int kk = 0; kk < 16; ++kk) acc += xs[ty][kk] * qs[tx][kk];
        __syncthreads();
    }
    if (m < M && n < N) out[(size_t)m * N + n] = scale[n] * acc + bias[n];
}

// ---------------------------------------------------------------------------
extern "C" void kernel_launch(void* const* d_in, const int* in_sizes, int n_in,
                              void* d_out, int out_size, void* d_ws, size_t ws_size,
                              hipStream_t stream)
{
    const float* x    = (const float*)d_in[0];
    const float* w    = (const float*)d_in[1];
    const float* bias = (const float*)d_in[2];
    float* out = (float*)d_out;

    const int N = in_sizes[2];             // OUT
    const int K = in_sizes[1] / N;         // IN
    const int M = in_sizes[0] / K;         // B

    const size_t scOff = 0;
    const size_t sxOff = (scOff + (size_t)N * 4 + 255) & ~(size_t)255;
    const size_t qOff  = (sxOff + (size_t)M * 4 + 255) & ~(size_t)255;
    const size_t xqOff = (qOff + (size_t)N * K + 255) & ~(size_t)255;
    const size_t need  = xqOff + (size_t)M * K;

    float* scale = (float*)((char*)d_ws + scOff);

    const bool fast = (ws_size >= need) &&
                      (M % BM == 0) && (N % BN == 0) && (K % BK == 0) &&
                      ((K & 3) == 0) && (K / BK >= 4) &&
                      (((M / BM) * (N / BN)) % 8 == 0);

    if (fast) {
        float* sx        = (float*)((char*)d_ws + sxOff);
        signed char* q   = (signed char*)((char*)d_ws + qOff);
        signed char* xq  = (signed char*)((char*)d_ws + xqOff);

        scale_quant_kernel<<<N, 256, 0, stream>>>(w, scale, q, K);
        x_quant_kernel<<<M, 256, 0, stream>>>(x, sx, xq, K);

        const int grid = (M / BM) * (N / BN);
        gemm256_i8_kernel<<<grid, 512, 0, stream>>>(xq, q, sx, scale, bias, out, M, N, K);
    } else {
        scale_quant_kernel<<<N, 256, 0, stream>>>(w, scale, nullptr, K);
        dim3 g((N + 15) / 16, (M + 15) / 16);
        fb_gemm_kernel<<<g, 256, 0, stream>>>(x, w, scale, bias, out, M, N, K);
    }
}